// Round 16
// baseline (161.622 us; speedup 1.0000x reference)
//
#include <hip/hip_runtime.h>
#include <hip/hip_cooperative_groups.h>

namespace cg = cooperative_groups;

// bpd_cuda: super-BPD boundary angle diff, 512x512. R16: ONE cooperative kernel.
//  Phase A (k_local logic): per 32x32 tile (1024 thr = 1 px/thread): pf inline,
//          LDS union-find over intra-tile edges (dh=0 nearest-right-root; dh in
//          {1,2} leftmost+rightmost in-tile root of 6-wide segment — proven
//          equivalent), publish depth-1 par, interior c3 via local-id chase.
//  Phase B (k_edges logic): band scan (270 px/tile): cross-tile edges deduped via
//          256-slot LDS hash; fresh pairs -> direct global uf_unite (monotone).
//  Phase C (k_output logic): per 32x32 tile: 33x33 label apron via find_ro walks
//          (compression fused), diff vs right/down, c3 from array (interior) or
//          pf^3 chase (band).
// grid.sync() between phases replaces two kernel-launch gaps (R15: 3 dispatches).
// Labels are only compared for equality, so any consistent representative works.
// All par mutations: atomicMin hooks (monotone) or final-value plain stores.

static constexpr double PI_D = 3.14159265;
#define NB 256
#define NT 1024

__device__ __constant__ int c_DH[8] = {1, 1, 0, -1, -1, -1, 0, 1};
__device__ __constant__ int c_DW[8] = {0, 1, 1, 1, 0, -1, -1, -1};

// fallback scratch: pf, par, c3 (3N) for N<=262144
__device__ int g_fb[3 * 262144];

// ---- LDS union-find (atomicMin path-halving; cheap on-CU atomics) ----
__device__ __forceinline__ int uf_find_lds(int x, int* par) {
    while (true) {
        int p = par[x];
        if (p == x) return x;
        int gp = par[p];
        if (gp == p) return p;
        atomicMin(&par[x], gp);
        x = gp;
    }
}
__device__ __forceinline__ void uf_unite_lds(int u, int v, int* par) {
    int ru = uf_find_lds(u, par);
    int rv = uf_find_lds(v, par);
    while (ru != rv) {
        if (ru > rv) { int t2 = ru; ru = rv; rv = t2; }
        int old = atomicMin(&par[rv], ru);
        if (old == rv) break;
        rv = uf_find_lds(old, par);
        ru = uf_find_lds(ru, par);
    }
}

// ---- global union-find: read-only walks, RMW only on hooks (ECL-CC style) ----
__device__ __forceinline__ int find_ro(int x, const int* par) {
    int p = par[x];
    while (p != x) { x = p; p = par[x]; }
    return x;
}
__device__ __forceinline__ void uf_unite(int u, int v, int* par) {
    int ru = find_ro(u, par);
    int rv = find_ro(v, par);
    while (ru != rv) {
        if (ru > rv) { int t2 = ru; ru = rv; rv = t2; }
        int old = atomicMin(&par[rv], ru);
        if (old == rv) break;          // rv really was a root: linked
        rv = find_ro(old, par);        // rv was already hooked; merge that comp too
        ru = find_ro(ru, par);
    }
}

// per-pixel parent direction (bit-exact vs the JAX f32 reference)
__device__ __forceinline__ bool parent_dir(const float* __restrict__ ang, float a,
                                           int i, int j, int H, int W, float thr,
                                           int& nhc, int& nwc) {
    const float a8 = (float)(PI_D / 8.0);
    const float a4 = (float)(PI_D / 4.0);
    float posf = rintf((a + a8) / a4);        // jnp.round == round-half-even == rintf
    if (posf >= 8.0f) posf -= 8.0f;
    const int pos = (int)posf;
    const int nh = i + c_DH[pos];
    const int nw = j + c_DW[pos];
    const bool inb = (nh >= 0) & (nh < H) & (nw >= 0) & (nw < W);
    nhc = min(max(nh, 0), H - 1);
    nwc = min(max(nw, 0), W - 1);
    float ad = fabsf(a - ang[nhc * W + nwc]);
    const float twopi = (float)(2.0 * PI_D);
    ad = fminf(ad, twopi - ad);
    return (!inb) || (ad > thr);
}

__global__ void __launch_bounds__(NT, 1)
k_all(const float* __restrict__ ang,
      const int* __restrict__ hp, const int* __restrict__ wp,
      const int* __restrict__ tap, int N,
      int* __restrict__ pf, int* par, int* __restrict__ c3,
      float* __restrict__ out) {
    const int H = hp[0], W = wp[0];
    const float thr = (float)((double)tap[0] * PI_D / 180.0);
    const int tpr = (W + 31) >> 5;
    const int ntiles = tpr * ((H + 31) >> 5);
    __shared__ int lpar[1024];
    __shared__ int lpl[1024];    // local parent id; -1 = parent out-of-tile; lp = root
    __shared__ unsigned long long htab[256];
    __shared__ int lab[33][33];
    const int lp = threadIdx.x;
    const int li = lp >> 5, lj = lp & 31;

    // ---------- Phase A: per-tile CC in LDS ----------
    for (int tile = blockIdx.x; tile < ntiles; tile += gridDim.x) {
        const int ti0 = (tile / tpr) << 5, tj0 = (tile % tpr) << 5;
        const int i = ti0 + li, j = tj0 + lj;
        const bool inpix = (i < H) && (j < W);
        const int g = i * W + j;
        lpar[lp] = lp;
        int lparent = lp;                 // default: treat as root
        if (inpix) {
            int nh, nw;
            const bool root = parent_dir(ang, ang[g], i, j, H, W, thr, nh, nw);
            pf[g] = root ? g : (nh * W + nw);
            if (!root) {
                const int pli = nh - ti0, plj = nw - tj0;
                lparent = (((unsigned)pli < 32u) && ((unsigned)plj < 32u))
                              ? ((pli << 5) + plj) : -1;
            }
        }
        lpl[lp] = lparent;
        __syncthreads();
        if (inpix) {
            if (lparent != lp) {                       // non-root
                if (lparent >= 0) uf_unite_lds(lp, lparent, lpar);
            } else if (i <= H - 2) {                   // root: window edges
                // dh=0: nearest in-tile right root within 3 (transitively complete)
                for (int d = 1; d <= 3; ++d) {
                    if (lj + d > 31 || j + d > W - 1) break;
                    if (lpl[lp + d] == lp + d) { uf_unite_lds(lp, lp + d, lpar); break; }
                }
                // dh in {1,2}: leftmost + rightmost in-tile root of 6-wide segment
                for (int dh = 1; dh <= 2; ++dh) {
                    const int nh = i + dh;
                    if (nh > H - 2) break;
                    const int nli = li + dh;
                    if (nli >= 32) break;
                    int first = -1, last = -1;
                    for (int dw = -3; dw <= 2; ++dw) {
                        const int nw = j + dw;
                        if ((unsigned)nw > (unsigned)(W - 2)) continue;
                        const int nlj = lj + dw;
                        if ((unsigned)nlj > 31u) continue;
                        const int nlp = (nli << 5) + nlj;
                        if (lpl[nlp] == nlp) { if (first < 0) first = nlp; last = nlp; }
                    }
                    if (first >= 0) {
                        uf_unite_lds(lp, first, lpar);
                        if (last != first) uf_unite_lds(lp, last, lpar);
                    }
                }
            }
        }
        __syncthreads();
        if (inpix) {
            const int lr = uf_find_lds(lp, lpar);
            par[g] = (ti0 + (lr >> 5)) * W + (tj0 + (lr & 31));
            // interior px: 3-hop chase stays in-tile (distance <= 3) -> local ids
            if (li >= 3 && li <= 28 && lj >= 3 && lj <= 28) {
                int v = lpl[lp];
                v = lpl[v];
                v = lpl[v];
                c3[g] = (ti0 + (v >> 5)) * W + (tj0 + (v & 31));
            }
        }
        __syncthreads();   // protect LDS re-init on next iteration
    }
    cg::this_grid().sync();

    // ---------- Phase B: cross-tile unions (deduped via LDS hash) ----------
    {
        int bi = 0, bj = 0;
        const int tidx = lp;
        if (tidx < 96) {                       // rows {0,30,31}, all 32 cols
            const int r = tidx >> 5;
            bi = (r == 0) ? 0 : 29 + r;
            bj = tidx & 31;
        } else if (tidx < 270) {               // rows 1..29, cols {0,1,2,29,30,31}
            const int u = tidx - 96;
            bi = 1 + u / 6;
            const int c = u % 6;
            bj = (c < 3) ? c : 26 + c;
        }
        for (int tile = blockIdx.x; tile < ntiles; tile += gridDim.x) {
            for (int s = tidx; s < 256; s += NT) htab[s] = ~0ull;
            __syncthreads();
            const int i = ((tile / tpr) << 5) + bi;
            const int j = ((tile % tpr) << 5) + bj;
            if (tidx < 270 && i < H && j < W) {
                const int t = i * W + j;
                auto EMIT = [&](int a, int b) {   // a,b: tile-root px ids, diff tiles
                    if (a == b) return;
                    const int lo = min(a, b), hi2 = max(a, b);
                    const unsigned long long key =
                        ((unsigned long long)lo << 20) | (unsigned)hi2;   // N < 2^20
                    unsigned h = (unsigned)((key * 0x9E3779B97F4A7C15ull) >> 52) & 255u;
                    bool fresh = true;
                    for (int pr = 0; pr < 16; ++pr) {
                        unsigned long long old = atomicCAS(&htab[h], ~0ull, key);
                        if (old == ~0ull) break;                 // inserted (new)
                        if (old == key) { fresh = false; break; }
                        h = (h + 1) & 255u;                      // probe (full: dup ok)
                    }
                    if (fresh) uf_unite(lo, hi2, par);           // monotone hook
                };
                const int p = pf[t];
                if (p != t) {                                    // cross-tile parent
                    const int pi = p / W, pj = p - pi * W;
                    if (((pi ^ i) | (pj ^ j)) & ~31) EMIT(par[t], par[p]);
                } else if (i <= H - 2) {
                    const int pt = par[t];
                    int h0 = -1, h1 = -1;
                    // dh=0 dedup'd rightward, cross-tile only (bj+d>31)
                    for (int d = (bj >= 29 ? 32 - bj : 4); d <= 3; ++d) {
                        if (j + d > W - 1) break;
                        const int n = t + d;
                        if (pf[n] != n) continue;
                        const int pn = par[n];
                        if (pn == pt || pn == h0 || pn == h1) continue;
                        h1 = h0; h0 = pn;
                        EMIT(pt, pn);
                    }
                    // dh in {1,2}
                    for (int dh = 1; dh <= 2; ++dh) {
                        const int nh = i + dh;
                        if (nh > H - 2) break;
                        const bool rowcross = (bi + dh) > 31;
                        for (int dw = -3; dw <= 2; ++dw) {
                            const int nw = j + dw;
                            if ((unsigned)nw > (unsigned)(W - 2)) continue;
                            if (!rowcross && ((unsigned)(bj + dw) <= 31u)) continue;
                            const int n = nh * W + nw;
                            if (pf[n] != n) continue;
                            const int pn = par[n];
                            if (pn == pt || pn == h0 || pn == h1) continue;
                            h1 = h0; h0 = pn;
                            EMIT(pt, pn);
                        }
                    }
                }
            }
            __syncthreads();   // protect htab re-init on next iteration
        }
    }
    cg::this_grid().sync();

    // ---------- Phase C: output (33x33 label apron per 32x32 tile) ----------
    const float twopi = (float)(2.0 * PI_D);
    for (int tile = blockIdx.x; tile < ntiles; tile += gridDim.x) {
        const int ti0 = (tile / tpr) << 5, tj0 = (tile % tpr) << 5;
        for (int k = lp; k < 33 * 33; k += NT) {
            const int r = k / 33, c = k - r * 33;
            const int gi = min(ti0 + r, H - 1), gj = min(tj0 + c, W - 1);
            lab[r][c] = find_ro(gi * W + gj, par);   // unions complete after sync
        }
        __syncthreads();
        const int i = ti0 + li, j = tj0 + lj;
        if (i < H && j < W) {
            const int t = i * W + j;
            const int l = lab[li][lj];
            float r0 = 0.0f, r1 = 0.0f;
            bool need = false;
            int l1 = l, l2 = l;
            if (j + 1 < W) { l1 = lab[li][lj + 1]; need |= (l1 != l); }
            if (i + 1 < H) { l2 = lab[li + 1][lj]; need |= (l2 != l); }
            if (need) {
                auto c3v = [&](int x, int xli, int xlj) {  // local coords in x's tile
                    if (xli >= 3 && xli <= 28 && xlj >= 3 && xlj <= 28) return c3[x];
                    int p = pf[x];
                    p = pf[p];
                    return pf[p];
                };
                const float ac = ang[c3v(t, li, lj)];
                if (l1 != l) {
                    float ad = fabsf(ac - ang[c3v(t + 1, li, (j + 1) & 31)]);
                    r0 = fminf(ad, twopi - ad);
                }
                if (l2 != l) {
                    float ad = fabsf(ac - ang[c3v(t + W, (i + 1) & 31, lj)]);
                    r1 = fminf(ad, twopi - ad);
                }
            }
            reinterpret_cast<float2*>(out)[t] = make_float2(r0, r1);
        }
        __syncthreads();   // protect lab re-init on next iteration
    }
}

extern "C" void kernel_launch(void* const* d_in, const int* in_sizes, int n_in,
                              void* d_out, int out_size, void* d_ws, size_t ws_size,
                              hipStream_t stream) {
    const float* ang = (const float*)d_in[0];
    const int* hp  = (const int*)d_in[1];
    const int* wp  = (const int*)d_in[2];
    const int* tap = (const int*)d_in[3];
    int N = in_sizes[0];

    int* base = (int*)d_ws;
    if (ws_size < (size_t)3 * (size_t)N * sizeof(int) && N <= 262144) {
        void* p = nullptr;
        hipGetSymbolAddress(&p, HIP_SYMBOL(g_fb));   // host-side query; capture-safe
        base = (int*)p;
    }
    int* pf  = base;
    int* par = base + N;
    int* c3  = base + 2 * N;
    float* op = (float*)d_out;

    void* kargs[] = {(void*)&ang, (void*)&hp, (void*)&wp, (void*)&tap,
                     (void*)&N, (void*)&pf, (void*)&par, (void*)&c3, (void*)&op};
    hipLaunchCooperativeKernel((const void*)k_all, dim3(NB), dim3(NT), kargs, 0, stream);
}

// Round 17
// 96.205 us; speedup vs baseline: 1.6800x; 1.6800x over previous
//
#include <hip/hip_runtime.h>

// bpd_cuda: super-BPD boundary angle diff, 512x512. R17: R15 + pointer-doubling CC.
//  k_local  : per 32x32 tile (1024 thr): pf inline; POINTER DOUBLING (6 in-place
//             rounds) resolves each pixel's chain terminal; UF only over true-root
//             window edges; SAFETY NET: any (pixel,parent) edge whose terminals
//             still differ (under-convergence or pf cycles) is united explicitly —
//             exact for any input, ~0 unions on the common path. Publish depth<=2
//             par; interior c3 via local-id chase.
//  k_edges  : band scan (270 px/tile): cross-tile edges deduped via 256-slot LDS
//             hash; fresh pairs -> direct global uf_unite (monotone atomicMin).
//  k_output : 32x8 px per block; 33x9 label apron via find_ro walks (compression
//             fused); c3 from array (interior) or pf^3 chase (band).
// Labels are only compared for equality, so any consistent representative works.
// All par mutations: atomicMin hooks (monotone) or final-value plain stores.

static constexpr double PI_D = 3.14159265;

__device__ __constant__ int c_DH[8] = {1, 1, 0, -1, -1, -1, 0, 1};
__device__ __constant__ int c_DW[8] = {0, 1, 1, 1, 0, -1, -1, -1};

// fallback scratch: pf, par, c3 (3N) for N<=262144
__device__ int g_fb[3 * 262144];

// ---- LDS union-find (atomicMin path-halving; cheap on-CU atomics) ----
__device__ __forceinline__ int uf_find_lds(int x, int* par) {
    while (true) {
        int p = par[x];
        if (p == x) return x;
        int gp = par[p];
        if (gp == p) return p;
        atomicMin(&par[x], gp);
        x = gp;
    }
}
__device__ __forceinline__ void uf_unite_lds(int u, int v, int* par) {
    int ru = uf_find_lds(u, par);
    int rv = uf_find_lds(v, par);
    while (ru != rv) {
        if (ru > rv) { int t2 = ru; ru = rv; rv = t2; }
        int old = atomicMin(&par[rv], ru);
        if (old == rv) break;
        rv = uf_find_lds(old, par);
        ru = uf_find_lds(ru, par);
    }
}

// ---- global union-find: read-only walks, RMW only on hooks (ECL-CC style) ----
__device__ __forceinline__ int find_ro(int x, const int* par) {
    int p = par[x];
    while (p != x) { x = p; p = par[x]; }
    return x;
}
__device__ __forceinline__ void uf_unite(int u, int v, int* par) {
    int ru = find_ro(u, par);
    int rv = find_ro(v, par);
    while (ru != rv) {
        if (ru > rv) { int t2 = ru; ru = rv; rv = t2; }
        int old = atomicMin(&par[rv], ru);
        if (old == rv) break;          // rv really was a root: linked
        rv = find_ro(old, par);        // rv was already hooked; merge that comp too
        ru = find_ro(ru, par);
    }
}

// per-pixel parent direction (bit-exact vs the JAX f32 reference)
__device__ __forceinline__ bool parent_dir(const float* __restrict__ ang, float a,
                                           int i, int j, int H, int W, float thr,
                                           int& nhc, int& nwc) {
    const float a8 = (float)(PI_D / 8.0);
    const float a4 = (float)(PI_D / 4.0);
    float posf = rintf((a + a8) / a4);        // jnp.round == round-half-even == rintf
    if (posf >= 8.0f) posf -= 8.0f;
    const int pos = (int)posf;
    const int nh = i + c_DH[pos];
    const int nw = j + c_DW[pos];
    const bool inb = (nh >= 0) & (nh < H) & (nw >= 0) & (nw < W);
    nhc = min(max(nh, 0), H - 1);
    nwc = min(max(nw, 0), W - 1);
    float ad = fabsf(a - ang[nhc * W + nwc]);
    const float twopi = (float)(2.0 * PI_D);
    ad = fminf(ad, twopi - ad);
    return (!inb) || (ad > thr);
}

// one 32x32 tile per block, 1024 threads = 1 px each
__global__ void __launch_bounds__(1024)
k_local(const float* __restrict__ ang,
        const int* __restrict__ hp, const int* __restrict__ wp,
        const int* __restrict__ tap, int N,
        int* __restrict__ pf, int* __restrict__ par, int* __restrict__ c3) {
    const int H = hp[0], W = wp[0];
    const float thr = (float)((double)tap[0] * PI_D / 180.0);
    const int tpr = (W + 31) >> 5;
    const int ntiles = tpr * ((H + 31) >> 5);
    __shared__ int lpar[1024];
    __shared__ int lpl[1024];   // local parent id; -1 = parent out-of-tile; lp = root
    __shared__ int nxt[1024];   // doubling pointer -> chain terminal
    const int lp = threadIdx.x;
    const int li = lp >> 5, lj = lp & 31;
    for (int tile = blockIdx.x; tile < ntiles; tile += gridDim.x) {
        const int ti0 = (tile / tpr) << 5, tj0 = (tile % tpr) << 5;
        const int i = ti0 + li, j = tj0 + lj;
        const bool inpix = (i < H) && (j < W);
        const int g = i * W + j;
        lpar[lp] = lp;
        int lparent = lp;                 // default: treat as root
        if (inpix) {
            int nh, nw;
            const bool root = parent_dir(ang, ang[g], i, j, H, W, thr, nh, nw);
            pf[g] = root ? g : (nh * W + nw);
            if (!root) {
                const int pli = nh - ti0, plj = nw - tj0;
                lparent = (((unsigned)pli < 32u) && ((unsigned)plj < 32u))
                              ? ((pli << 5) + plj) : -1;
            }
        }
        lpl[lp] = lparent;
        nxt[lp] = (lparent >= 0) ? lparent : lp;   // roots/exit-heads: self
        __syncthreads();
        // pointer doubling, in-place: racy reads only ever see valid (further)
        // ancestors — monotone. 6 rounds covers depth 64; deeper chains (or the
        // theoretical pf cycles) are caught by the safety net below.
        for (int rnd = 0; rnd < 6; ++rnd) {
            nxt[lp] = nxt[nxt[lp]];
            __syncthreads();
        }
        if (inpix) {
            // safety net: unite terminals across any unresolved (pixel,parent) edge
            if (lparent >= 0 && lparent != lp) {
                const int a = nxt[lp], b = nxt[lparent];
                if (a != b) uf_unite_lds(a, b, lpar);
            } else if (lparent == lp && i <= H - 2) {   // true root: window edges
                // dh=0: nearest in-tile right root within 3 (transitively complete)
                for (int d = 1; d <= 3; ++d) {
                    if (lj + d > 31 || j + d > W - 1) break;
                    if (lpl[lp + d] == lp + d) { uf_unite_lds(lp, lp + d, lpar); break; }
                }
                // dh in {1,2}: leftmost + rightmost in-tile root of 6-wide segment
                for (int dh = 1; dh <= 2; ++dh) {
                    const int nh = i + dh;
                    if (nh > H - 2) break;
                    const int nli = li + dh;
                    if (nli >= 32) break;
                    int first = -1, last = -1;
                    for (int dw = -3; dw <= 2; ++dw) {
                        const int nw = j + dw;
                        if ((unsigned)nw > (unsigned)(W - 2)) continue;
                        const int nlj = lj + dw;
                        if ((unsigned)nlj > 31u) continue;
                        const int nlp = (nli << 5) + nlj;
                        if (lpl[nlp] == nlp) { if (first < 0) first = nlp; last = nlp; }
                    }
                    if (first >= 0) {
                        uf_unite_lds(lp, first, lpar);
                        if (last != first) uf_unite_lds(lp, last, lpar);
                    }
                }
            }
        }
        __syncthreads();
        if (inpix) {
            const int lr = uf_find_lds(nxt[lp], lpar);
            par[g] = (ti0 + (lr >> 5)) * W + (tj0 + (lr & 31));
            // interior px: 3-hop chase stays in-tile (distance <= 3) -> local ids
            if (li >= 3 && li <= 28 && lj >= 3 && lj <= 28) {
                int v = lpl[lp];
                v = lpl[v];
                v = lpl[v];
                c3[g] = (ti0 + (v >> 5)) * W + (tj0 + (v & 31));
            }
        }
        __syncthreads();   // protect LDS re-init on next iteration
    }
}

// band scan: dedup cross-tile edges via LDS hash; fresh pairs -> direct global unite
__global__ void k_edges(const int* __restrict__ pf,
                        const int* __restrict__ hp, const int* __restrict__ wp,
                        int N, int* par) {
    const int H = hp[0], W = wp[0];
    const int tpr = (W + 31) >> 5;
    const int ntiles = tpr * ((H + 31) >> 5);
    const int tidx = threadIdx.x;
    __shared__ unsigned long long htab[256];
    int li = 0, lj = 0;
    if (tidx < 96) {                       // rows {0,30,31}, all 32 cols
        const int r = tidx >> 5;
        li = (r == 0) ? 0 : 29 + r;
        lj = tidx & 31;
    } else if (tidx < 270) {               // rows 1..29, cols {0,1,2,29,30,31}
        const int u = tidx - 96;
        li = 1 + u / 6;
        const int c = u % 6;
        lj = (c < 3) ? c : 26 + c;
    }
    for (int tile = blockIdx.x; tile < ntiles; tile += gridDim.x) {
        for (int s = tidx; s < 256; s += blockDim.x) htab[s] = ~0ull;
        __syncthreads();
        const int i = ((tile / tpr) << 5) + li;
        const int j = ((tile % tpr) << 5) + lj;
        if (tidx < 270 && i < H && j < W) {
            const int t = i * W + j;
            auto EMIT = [&](int a, int b) {   // a,b: tile-root pixel ids, diff tiles
                if (a == b) return;
                const int lo = min(a, b), hi2 = max(a, b);
                const unsigned long long key =
                    ((unsigned long long)lo << 20) | (unsigned)hi2;   // N < 2^20
                unsigned h = (unsigned)((key * 0x9E3779B97F4A7C15ull) >> 52) & 255u;
                bool fresh = true;
                for (int pr = 0; pr < 16; ++pr) {
                    unsigned long long old = atomicCAS(&htab[h], ~0ull, key);
                    if (old == ~0ull) break;                 // inserted (new)
                    if (old == key) { fresh = false; break; }
                    h = (h + 1) & 255u;                      // probe (full: dup ok)
                }
                if (fresh) uf_unite(lo, hi2, par);           // monotone hook
            };
            const int p = pf[t];
            if (p != t) {                                    // parent edge if cross-tile
                const int pi = p / W, pj = p - pi * W;
                if (((pi ^ i) | (pj ^ j)) & ~31) EMIT(par[t], par[p]);
            } else if (i <= H - 2) {
                const int pt = par[t];
                int h0 = -1, h1 = -1;
                // dh=0 dedup'd rightward, cross-tile only (lj+d>31)
                for (int d = (lj >= 29 ? 32 - lj : 4); d <= 3; ++d) {
                    if (j + d > W - 1) break;
                    const int n = t + d;
                    if (pf[n] != n) continue;
                    const int pn = par[n];
                    if (pn == pt || pn == h0 || pn == h1) continue;
                    h1 = h0; h0 = pn;
                    EMIT(pt, pn);
                }
                // dh in {1,2}
                for (int dh = 1; dh <= 2; ++dh) {
                    const int nh = i + dh;
                    if (nh > H - 2) break;
                    const bool rowcross = (li + dh) > 31;
                    for (int dw = -3; dw <= 2; ++dw) {
                        const int nw = j + dw;
                        if ((unsigned)nw > (unsigned)(W - 2)) continue;
                        if (!rowcross && ((unsigned)(lj + dw) <= 31u)) continue;
                        const int n = nh * W + nw;
                        if (pf[n] != n) continue;
                        const int pn = par[n];
                        if (pn == pt || pn == h0 || pn == h1) continue;
                        h1 = h0; h0 = pn;
                        EMIT(pt, pn);
                    }
                }
            }
        }
        __syncthreads();   // protect htab re-init on next iteration
    }
}

// 32x8 px per block; 33x9 label apron via find_ro walks (compression fused here)
__global__ void __launch_bounds__(256)
k_output(const float* __restrict__ ang,
         const int* __restrict__ par, const int* __restrict__ pf,
         const int* __restrict__ c3,
         const int* __restrict__ hp, const int* __restrict__ wp,
         float* __restrict__ out) {
    const int H = hp[0], W = wp[0];
    const int i0 = blockIdx.y << 3;
    const int j0 = blockIdx.x << 5;
    __shared__ int lab[9][33];
    const int tid = threadIdx.x;
    for (int k = tid; k < 9 * 33; k += 256) {
        const int r = k / 33, c = k - r * 33;
        const int gi = min(i0 + r, H - 1), gj = min(j0 + c, W - 1);
        lab[r][c] = find_ro(gi * W + gj, par);   // walk: unions complete at boundary
    }
    __syncthreads();
    const int li2 = tid >> 5, lj2 = tid & 31;
    const int i = i0 + li2, j = j0 + lj2;
    if (i >= H || j >= W) return;
    const int t = i * W + j;
    const float twopi = (float)(2.0 * PI_D);
    const int l = lab[li2][lj2];
    float r0 = 0.0f, r1 = 0.0f;
    bool need = false;
    int l1 = l, l2 = l;
    if (j + 1 < W) { l1 = lab[li2][lj2 + 1]; need |= (l1 != l); }
    if (i + 1 < H) { l2 = lab[li2 + 1][lj2]; need |= (l2 != l); }
    if (need) {
        auto c3v = [&](int x, int xli, int xlj) {   // xli/xlj: 32-tile local coords
            if (xli >= 3 && xli <= 28 && xlj >= 3 && xlj <= 28) return c3[x];
            int p = pf[x];
            p = pf[p];
            return pf[p];
        };
        const float ac = ang[c3v(t, i & 31, j & 31)];
        if (l1 != l) {
            float ad = fabsf(ac - ang[c3v(t + 1, i & 31, (j + 1) & 31)]);
            r0 = fminf(ad, twopi - ad);
        }
        if (l2 != l) {
            float ad = fabsf(ac - ang[c3v(t + W, (i + 1) & 31, j & 31)]);
            r1 = fminf(ad, twopi - ad);
        }
    }
    reinterpret_cast<float2*>(out)[t] = make_float2(r0, r1);
}

extern "C" void kernel_launch(void* const* d_in, const int* in_sizes, int n_in,
                              void* d_out, int out_size, void* d_ws, size_t ws_size,
                              hipStream_t stream) {
    const float* ang = (const float*)d_in[0];
    const int* hp  = (const int*)d_in[1];
    const int* wp  = (const int*)d_in[2];
    const int* tap = (const int*)d_in[3];
    const int N = in_sizes[0];

    int* base = (int*)d_ws;
    if (ws_size < (size_t)3 * (size_t)N * sizeof(int) && N <= 262144) {
        void* p = nullptr;
        hipGetSymbolAddress(&p, HIP_SYMBOL(g_fb));   // host-side query; capture-safe
        base = (int*)p;
    }
    int* pf  = base;
    int* par = base + N;
    int* c3  = base + 2 * N;

    // Grid shapes assume 512x512 (harness-fixed); kernels bounds-check vs hp/wp.
    k_local<<<256, 1024, 0, stream>>>(ang, hp, wp, tap, N, pf, par, c3);
    k_edges<<<256, 320, 0, stream>>>(pf, hp, wp, N, par);
    {
        const int H = 512, W = 512;
        dim3 gridO((W + 31) / 32, (H + 7) / 8);
        k_output<<<gridO, 256, 0, stream>>>(ang, par, pf, c3, hp, wp, (float*)d_out);
    }
}